// Round 7
// baseline (202.950 us; speedup 1.0000x reference)
//
#include <hip/hip_runtime.h>

#define N_NODES 100000
#define N_EDGES 1600000
#define D 64
#define NB 782                 // ceil(100000/128) dst-buckets of 128 nodes
#define CAP 3072               // slab slots per bucket (mean 2048, sigma~45)
#define EPB 8192               // edges per partition block
#define NPART ((N_EDGES + EPB - 1) / EPB)   // 196
#define RSH 14                 // src-range shift (keeps round-6 sort key)

typedef unsigned short ushort_t;
typedef unsigned int uint_t;

// ---------- K1: repack feat -> bf16 (RNE) + init gcur ----------
__device__ __forceinline__ ushort_t f2bf(float f) {
    uint_t u = __float_as_uint(f);
    u += 0x7FFF + ((u >> 16) & 1);          // round-nearest-even
    return (ushort_t)(u >> 16);
}

__global__ __launch_bounds__(256) void repack_init(const float* __restrict__ feat,
                                                   ushort_t* __restrict__ featb,
                                                   int* __restrict__ gcur) {
    const int tid = blockIdx.x * 256 + threadIdx.x;
    if (tid < NB) gcur[tid] = tid * CAP;
    const int base = tid * 16;              // 16 floats per thread
    if (base >= N_NODES * D) return;
    const float4* f4 = (const float4*)(feat + base);
    ushort4* o4 = (ushort4*)(featb + base);
#pragma unroll
    for (int j = 0; j < 4; ++j) {
        const float4 v = f4[j];
        o4[j] = make_ushort4(f2bf(v.x), f2bf(v.y), f2bf(v.z), f2bf(v.w));
    }
}

// ---------- K2: partition edges into per-bucket slabs ----------
__global__ __launch_bounds__(1024) void partition(const int* __restrict__ esrc,
                                                  const int* __restrict__ edst,
                                                  int* __restrict__ gcur,
                                                  int* __restrict__ slab) {
    __shared__ int stage[EPB];              // 32 KB: packed, sorted by bucket
    __shared__ ushort_t bkt16[EPB];         // 16 KB: bucket of sorted pos
    __shared__ int cnt[NB];
    __shared__ int cur[NB];
    __shared__ int gb[NB];
    __shared__ int s[1024];
    const int t = threadIdx.x;
    const int base = blockIdx.x * EPB;
    const int n = min(EPB, N_EDGES - base);

    if (t < NB) cnt[t] = 0;
    __syncthreads();
    for (int i = t; i < n; i += 1024)
        atomicAdd(&cnt[edst[base + i] >> 7], 1);
    __syncthreads();
    const int v = (t < NB) ? cnt[t] : 0;
    s[t] = v;
    __syncthreads();
    for (int off = 1; off < 1024; off <<= 1) {
        const int x = (t >= off) ? s[t - off] : 0;
        __syncthreads();
        s[t] += x;
        __syncthreads();
    }
    if (t < NB) {
        const int excl = s[t] - v;
        cur[t] = excl;
        gb[t] = (v ? atomicAdd(&gcur[t], v) : 0) - excl;
    }
    __syncthreads();
    for (int i = t; i < n; i += 1024) {     // coalesced re-read (L2-hot)
        const int d = edst[base + i];
        const int bkt = d >> 7;
        const int pos = atomicAdd(&cur[bkt], 1);
        stage[pos] = ((d & 127) << 17) | esrc[base + i];
        bkt16[pos] = (ushort_t)bkt;
    }
    __syncthreads();
    for (int i = t; i < n; i += 1024) {     // coalesced segment writes
        const int bkt = bkt16[i];
        const int gp = gb[bkt] + i;
        if (gp < (bkt + 1) * CAP)           // overflow guard (never expected)
            slab[gp] = stage[i];
    }
}

// ---------- 8-lane all-reduce on the VALU pipe (DPP, no DS ops) ----------
template<int CTRL>
__device__ __forceinline__ float fadd_dpp(float x) {
    const int r = __builtin_amdgcn_update_dpp(0, __float_as_int(x), CTRL, 0xF, 0xF, true);
    return x + __int_as_float(r);
}
__device__ __forceinline__ float red8(float p) {
    p = fadd_dpp<0xB1>(p);    // quad_perm [1,0,3,2]  : xor 1
    p = fadd_dpp<0x4E>(p);    // quad_perm [2,3,0,1]  : xor 2
    p = fadd_dpp<0x141>(p);   // row_half_mirror      : xor within 8
    return p;
}

__device__ __forceinline__ void cvt8(const uint4 u, float* __restrict__ g) {
    g[0] = __uint_as_float(u.x << 16); g[1] = __uint_as_float(u.x & 0xFFFF0000u);
    g[2] = __uint_as_float(u.y << 16); g[3] = __uint_as_float(u.y & 0xFFFF0000u);
    g[4] = __uint_as_float(u.z << 16); g[5] = __uint_as_float(u.z & 0xFFFF0000u);
    g[6] = __uint_as_float(u.w << 16); g[7] = __uint_as_float(u.w & 0xFFFF0000u);
}
__device__ __forceinline__ float cvt_dot(const uint4 u, const float* __restrict__ h,
                                         float* __restrict__ g) {
    cvt8(u, g);
    float p = 0.f;
#pragma unroll
    for (int k = 0; k < 8; ++k) p += g[k] * h[k];
    return p;
}

// ---------- K3: fused SDDMM + SpMM + GEMM ----------
// One 128-node bucket per block. Phase A: counting-sort to per-node CSR in
// LDS. Phase B: 8-lane node slots, bf16 gathers, unroll-4 MLP, register
// accumulate; acc dumped into LDS tile overlaid on the (dead) sort scratch.
// Phase C: block GEMM 128x64 @ W^T from LDS -> out. neigh never hits HBM.
__global__ __launch_bounds__(512) void fused_spmm_gemm(
    const uint4* __restrict__ featb4,
    const int* __restrict__ slab,
    const int* __restrict__ gcur,
    const float* __restrict__ W,
    float* __restrict__ out)
{
    __shared__ __align__(16) char ovl[32768];   // A: seA/kcnt/kcur/s  C: accs
    __shared__ int seB[CAP];                    // 12 KB
    __shared__ int rowoff[129];
    int* seA     = (int*)ovl;                   // [0, 12288)
    int* kcnt    = (int*)(ovl + 12288);         // 1024 ints
    int* kcur    = (int*)(ovl + 16384);         // 1024 ints
    int* s       = (int*)(ovl + 20480);         // 512 ints
    float* accs  = (float*)ovl;                 // phase C: 128*64 floats
    float4* accs4 = (float4*)ovl;

    const int t = threadIdx.x;
    const int b = blockIdx.x;
    const int nbase = b << 7;
    const int nb_nodes = min(128, N_NODES - nbase);
    const int sbase = b * CAP;
    const int ne = min(gcur[b] - sbase, CAP);

    // ---- Phase A: sort by (local_dst, src>>RSH) ----
    for (int i = t; i < ne; i += 512) seA[i] = slab[sbase + i];
    kcnt[t] = 0; kcnt[t + 512] = 0;
    __syncthreads();
    for (int i = t; i < ne; i += 512) {
        const int pk = seA[i];
        atomicAdd(&kcnt[((pk >> 17) << 3) | ((pk & 0x1FFFF) >> RSH)], 1);
    }
    __syncthreads();
    const int v0 = kcnt[2 * t], v1 = kcnt[2 * t + 1];
    const int sum = v0 + v1;
    s[t] = sum;
    __syncthreads();
    for (int off = 1; off < 512; off <<= 1) {
        const int x = (t >= off) ? s[t - off] : 0;
        __syncthreads();
        s[t] += x;
        __syncthreads();
    }
    const int excl = s[t] - sum;
    kcur[2 * t] = excl;
    kcur[2 * t + 1] = excl + v0;
    __syncthreads();
    if (t < 128) rowoff[t] = kcur[t << 3];
    if (t == 0) rowoff[128] = ne;
    __syncthreads();
    for (int i = t; i < ne; i += 512) {
        const int pk = seA[i];
        const int key = ((pk >> 17) << 3) | ((pk & 0x1FFFF) >> RSH);
        const int pos = atomicAdd(&kcur[key], 1);
        seB[pos] = pk & 0x1FFFF;
    }
    __syncthreads();   // seA/kcnt/kcur/s dead from here -> accs may overwrite

    // ---- Phase B: edge loops, register accumulate ----
    const int slot = t >> 3;                // 64 node-slots per block
    const int l = t & 7;                    // lane owns dims 8l..8l+7
#pragma unroll
    for (int ln0 = 0; ln0 < 128; ln0 += 64) {
        const int ln = ln0 + slot;
        if (ln >= nb_nodes) continue;
        const int nidx = nbase + ln;
        float h[8];
        cvt8(featb4[nidx * 8 + l], h);      // hd from bf16 (L3-resident)
        float acc[8];
#pragma unroll
        for (int k = 0; k < 8; ++k) acc[k] = 0.f;

        int e = rowoff[ln];
        const int e1 = rowoff[ln + 1];
        for (; e + 3 < e1; e += 4) {
            const int s0 = seB[e], s1 = seB[e + 1], s2 = seB[e + 2], s3 = seB[e + 3];
            const uint4 u0 = featb4[s0 * 8 + l];   // 4 gathers in flight
            const uint4 u1 = featb4[s1 * 8 + l];
            const uint4 u2 = featb4[s2 * 8 + l];
            const uint4 u3 = featb4[s3 * 8 + l];
            float g0[8], g1[8], g2[8], g3[8];
            float p0 = cvt_dot(u0, h, g0);
            float p1 = cvt_dot(u1, h, g1);
            float p2 = cvt_dot(u2, h, g2);
            float p3 = cvt_dot(u3, h, g3);
            p0 = red8(p0); p1 = red8(p1); p2 = red8(p2); p3 = red8(p3);
#pragma unroll
            for (int k = 0; k < 8; ++k)
                acc[k] += g0[k] * p0 + g1[k] * p1 + g2[k] * p2 + g3[k] * p3;
        }
        for (; e < e1; ++e) {
            const uint4 u0 = featb4[seB[e] * 8 + l];
            float g0[8];
            float p0 = red8(cvt_dot(u0, h, g0));
#pragma unroll
            for (int k = 0; k < 8; ++k) acc[k] += g0[k] * p0;
        }
        accs4[ln * 16 + 2 * l]     = make_float4(acc[0], acc[1], acc[2], acc[3]);
        accs4[ln * 16 + 2 * l + 1] = make_float4(acc[4], acc[5], acc[6], acc[7]);
    }
    __syncthreads();

    // ---- Phase C: out[nbase+r, o] = sum_i accs[r][i] * W[o][i] ----
    // thread = (o = t&63, row-group rg = t>>6). W row o in 64 VGPRs
    // (L2-hot after first blocks); accs rows read as wave-broadcast float4.
    const int o = t & 63;
    const int rg = t >> 6;                  // 0..7
    float wcol[D];
    {
        const float4* W4 = (const float4*)(W + o * D);
#pragma unroll
        for (int i4 = 0; i4 < 16; ++i4) {
            const float4 w = W4[i4];
            wcol[4 * i4 + 0] = w.x; wcol[4 * i4 + 1] = w.y;
            wcol[4 * i4 + 2] = w.z; wcol[4 * i4 + 3] = w.w;
        }
    }
    for (int r = rg; r < nb_nodes; r += 8) {
        const float4* arow = (const float4*)&accs[r * D];
        float sumv = 0.f;
#pragma unroll
        for (int i4 = 0; i4 < 16; ++i4) {
            const float4 a4 = arow[i4];     // same addr across wave: broadcast
            sumv += a4.x * wcol[4 * i4 + 0];
            sumv += a4.y * wcol[4 * i4 + 1];
            sumv += a4.z * wcol[4 * i4 + 2];
            sumv += a4.w * wcol[4 * i4 + 3];
        }
        out[(nbase + r) * D + o] = sumv;    // coalesced per wave
    }
}

extern "C" void kernel_launch(void* const* d_in, const int* in_sizes, int n_in,
                              void* d_out, int out_size, void* d_ws, size_t ws_size,
                              hipStream_t stream) {
    const float* feat = (const float*)d_in[0];
    const int*   esrc = (const int*)d_in[1];
    const int*   edst = (const int*)d_in[2];
    const float* W    = (const float*)d_in[3];
    float* out = (float*)d_out;

    char* ws = (char*)d_ws;
    ushort_t* featb = (ushort_t*)(ws);                       // 12.8 MB
    int* slab = (int*)(ws + 12800000);                       // NB*CAP*4 = 9.61 MB
    int* gcur = (int*)(ws + 12800000 + (size_t)NB * CAP * 4);// 3.1 KB

    repack_init<<<(N_NODES * D / 16 + 255) / 256, 256, 0, stream>>>(feat, featb, gcur);
    partition<<<NPART, 1024, 0, stream>>>(esrc, edst, gcur, slab);
    fused_spmm_gemm<<<NB, 512, 0, stream>>>((const uint4*)featb, slab, gcur, W, out);
}